// Round 1
// baseline (1709.834 us; speedup 1.0000x reference)
//
#include <hip/hip_runtime.h>

// IrradianceVolumes: out[i,c] = relu( sum_j sh_j(normal_i) * trilerp(coeff[...,j,c], point_i) )
// coeff: [128,128,128,16,3] f32 (403 MB), points/normals: [2M,3] f32, out: [2M,3] f32.
// Memory-bound random gather: 8 corners x 192 B per point.

constexpr int RES = 128;
constexpr int D2 = 16;          // DEGREE^2
constexpr int CSTRIDE = D2 * 3; // 48 floats per cell

__global__ __launch_bounds__(256) void irradiance_kernel(
    const float* __restrict__ coeff,
    const float* __restrict__ aabb,
    const float* __restrict__ points,
    const float* __restrict__ normals,
    float* __restrict__ out,
    int n)
{
    const int i = blockIdx.x * blockDim.x + threadIdx.x;
    if (i >= n) return;

    const float px = points[3 * i + 0];
    const float py = points[3 * i + 1];
    const float pz = points[3 * i + 2];
    const float nx = normals[3 * i + 0];
    const float ny = normals[3 * i + 1];
    const float nz = normals[3 * i + 2];

    // aabb is uniform across threads -> scalar loads
    const float a0 = aabb[0], a1 = aabb[1], a2 = aabb[2];
    const float b0 = aabb[3], b1 = aabb[4], b2 = aabb[5];

    // grid coords (match reference order of ops)
    float gx = (px - a0) / (b0 - a0) * (float)(RES - 1);
    float gy = (py - a1) / (b1 - a1) * (float)(RES - 1);
    float gz = (pz - a2) / (b2 - a2) * (float)(RES - 1);
    gx = fminf(fmaxf(gx, 0.0f), (float)(RES - 1));
    gy = fminf(fmaxf(gy, 0.0f), (float)(RES - 1));
    gz = fminf(fmaxf(gz, 0.0f), (float)(RES - 1));

    const int ix = min((int)floorf(gx), RES - 2);
    const int iy = min((int)floorf(gy), RES - 2);
    const int iz = min((int)floorf(gz), RES - 2);
    const float fx = gx - (float)ix;
    const float fy = gy - (float)iy;
    const float fz = gz - (float)iz;

    // SH basis, degree 4 -> 16 components
    const float xx = nx * nx, yy = ny * ny, zz = nz * nz;
    const float xy = nx * ny, yz = ny * nz, xz = nx * nz;
    float sh[D2];
    sh[0]  = 0.28209479177387814f;
    sh[1]  = -0.4886025119029199f * ny;
    sh[2]  = 0.4886025119029199f * nz;
    sh[3]  = -0.4886025119029199f * nx;
    sh[4]  = 1.0925484305920792f * xy;
    sh[5]  = -1.0925484305920792f * yz;
    sh[6]  = 0.31539156525252005f * (2.0f * zz - xx - yy);
    sh[7]  = -1.0925484305920792f * xz;
    sh[8]  = 0.5462742152960396f * (xx - yy);
    sh[9]  = -0.5900435899266435f * ny * (3.0f * xx - yy);
    sh[10] = 2.890611442640554f * xy * nz;
    sh[11] = -0.4570457994644658f * ny * (4.0f * zz - xx - yy);
    sh[12] = 0.3731763325901154f * nz * (2.0f * zz - 3.0f * xx - 3.0f * yy);
    sh[13] = -0.4570457994644658f * nx * (4.0f * zz - xx - yy);
    sh[14] = 1.445305721320277f * nz * (xx - yy);
    sh[15] = -0.5900435899266435f * nx * (xx - 3.0f * yy);

    const float wz0 = 1.0f - fz, wz1 = fz;
    float acc0 = 0.0f, acc1 = 0.0f, acc2 = 0.0f;

#pragma unroll
    for (int dx = 0; dx < 2; ++dx) {
        const float wx = dx ? fx : 1.0f - fx;
#pragma unroll
        for (int dy = 0; dy < 2; ++dy) {
            const float wxy = wx * (dy ? fy : 1.0f - fy);
            // z-neighbors are contiguous: load both corners (96 floats = 384 B)
            // as 24 float4s. iz <= 126 so this stays in-bounds.
            const int cell = (((ix + dx) * RES + (iy + dy)) * RES + iz) * CSTRIDE;
            const float4* __restrict__ cp = (const float4*)(coeff + cell);
            union { float4 q[24]; float v[96]; } u;
#pragma unroll
            for (int k = 0; k < 24; ++k) u.q[k] = cp[k];

            float s00 = 0.f, s01 = 0.f, s02 = 0.f;  // dz = 0 corner dot
            float s10 = 0.f, s11 = 0.f, s12 = 0.f;  // dz = 1 corner dot
#pragma unroll
            for (int j = 0; j < D2; ++j) {
                const float s = sh[j];
                s00 = fmaf(s, u.v[3 * j + 0], s00);
                s01 = fmaf(s, u.v[3 * j + 1], s01);
                s02 = fmaf(s, u.v[3 * j + 2], s02);
                s10 = fmaf(s, u.v[48 + 3 * j + 0], s10);
                s11 = fmaf(s, u.v[48 + 3 * j + 1], s11);
                s12 = fmaf(s, u.v[48 + 3 * j + 2], s12);
            }
            const float w0 = wxy * wz0, w1 = wxy * wz1;
            acc0 = fmaf(w0, s00, fmaf(w1, s10, acc0));
            acc1 = fmaf(w0, s01, fmaf(w1, s11, acc1));
            acc2 = fmaf(w0, s02, fmaf(w1, s12, acc2));
        }
    }

    out[3 * i + 0] = fmaxf(acc0, 0.0f);
    out[3 * i + 1] = fmaxf(acc1, 0.0f);
    out[3 * i + 2] = fmaxf(acc2, 0.0f);
}

extern "C" void kernel_launch(void* const* d_in, const int* in_sizes, int n_in,
                              void* d_out, int out_size, void* d_ws, size_t ws_size,
                              hipStream_t stream) {
    const float* coeff   = (const float*)d_in[0];
    const float* aabb    = (const float*)d_in[1];
    const float* points  = (const float*)d_in[2];
    const float* normals = (const float*)d_in[3];
    float* out = (float*)d_out;

    const int n = in_sizes[2] / 3;  // N_PTS
    dim3 block(256);
    dim3 grid((n + 255) / 256);
    hipLaunchKernelGGL(irradiance_kernel, grid, block, 0, stream,
                       coeff, aabb, points, normals, out, n);
}

// Round 2
// 1606.761 us; speedup vs baseline: 1.0641x; 1.0641x over previous
//
#include <hip/hip_runtime.h>

// IrradianceVolumes: out[i,c] = relu( sum_j sh_j(normal_i) * trilerp(coeff[...,j,c], point_i) )
// coeff: [128,128,128,16,3] f32 (403 MB), points/normals: [2M,3] f32, out: [2M,3] f32.
//
// Round 2: spatial counting-sort of points into 16^3 bins (8^3 cells each) so the
// random gather becomes cache-resident. Round-1 fetched 4.1 GB for a 403 MB grid
// (each cell re-fetched ~10x); sorted processing should fetch the grid ~once.

constexpr int RES = 128;
constexpr int D2 = 16;          // DEGREE^2
constexpr int CSTRIDE = D2 * 3; // 48 floats per cell
constexpr int BIN_SHIFT = 3;    // 8^3 cells per bin
constexpr int BPA = 16;         // bins per axis = 128/8
constexpr int NBINS = BPA * BPA * BPA; // 4096

__device__ __forceinline__ void grid_coords(const float* aabb, float px, float py, float pz,
                                            int& ix, int& iy, int& iz,
                                            float& fx, float& fy, float& fz)
{
    const float a0 = aabb[0], a1 = aabb[1], a2 = aabb[2];
    const float b0 = aabb[3], b1 = aabb[4], b2 = aabb[5];
    float gx = (px - a0) / (b0 - a0) * (float)(RES - 1);
    float gy = (py - a1) / (b1 - a1) * (float)(RES - 1);
    float gz = (pz - a2) / (b2 - a2) * (float)(RES - 1);
    gx = fminf(fmaxf(gx, 0.0f), (float)(RES - 1));
    gy = fminf(fmaxf(gy, 0.0f), (float)(RES - 1));
    gz = fminf(fmaxf(gz, 0.0f), (float)(RES - 1));
    ix = min((int)floorf(gx), RES - 2);
    iy = min((int)floorf(gy), RES - 2);
    iz = min((int)floorf(gz), RES - 2);
    fx = gx - (float)ix;
    fy = gy - (float)iy;
    fz = gz - (float)iz;
}

// ---------------- pass 1: histogram + bin id per point ----------------
__global__ __launch_bounds__(256) void hist_kernel(
    const float* __restrict__ aabb,
    const float* __restrict__ points,
    int* __restrict__ bin_of_point,
    int* __restrict__ hist,
    int n)
{
    const int i = blockIdx.x * blockDim.x + threadIdx.x;
    if (i >= n) return;
    int ix, iy, iz; float fx, fy, fz;
    grid_coords(aabb, points[3 * i + 0], points[3 * i + 1], points[3 * i + 2],
                ix, iy, iz, fx, fy, fz);
    const int bin = (((ix >> BIN_SHIFT) * BPA) + (iy >> BIN_SHIFT)) * BPA + (iz >> BIN_SHIFT);
    bin_of_point[i] = bin;
    atomicAdd(&hist[bin], 1);
}

// ---------------- pass 2: exclusive prefix sum over 4096 bins ----------------
__global__ __launch_bounds__(256) void scan_kernel(
    const int* __restrict__ hist,
    int* __restrict__ cursor)
{
    __shared__ int lsum[256];
    const int t = threadIdx.x;
    const int base = t * (NBINS / 256); // 16 bins per thread
    int loc[NBINS / 256];
    int s = 0;
#pragma unroll
    for (int k = 0; k < NBINS / 256; ++k) { loc[k] = hist[base + k]; s += loc[k]; }
    lsum[t] = s;
    __syncthreads();
    // Hillis-Steele inclusive scan over 256 partials
    for (int off = 1; off < 256; off <<= 1) {
        int v = (t >= off) ? lsum[t - off] : 0;
        __syncthreads();
        lsum[t] += v;
        __syncthreads();
    }
    int run = lsum[t] - s; // exclusive prefix of this thread's chunk
#pragma unroll
    for (int k = 0; k < NBINS / 256; ++k) { cursor[base + k] = run; run += loc[k]; }
}

// ---------------- pass 3: scatter points into sorted order ----------------
__global__ __launch_bounds__(256) void scatter_kernel(
    const float* __restrict__ points,
    const float* __restrict__ normals,
    const int* __restrict__ bin_of_point,
    int* __restrict__ cursor,
    float* __restrict__ spx, float* __restrict__ spy, float* __restrict__ spz,
    float* __restrict__ snx, float* __restrict__ sny, float* __restrict__ snz,
    int* __restrict__ oidx,
    int n)
{
    const int i = blockIdx.x * blockDim.x + threadIdx.x;
    if (i >= n) return;
    const int bin = bin_of_point[i];
    const int pos = atomicAdd(&cursor[bin], 1);
    spx[pos] = points[3 * i + 0];
    spy[pos] = points[3 * i + 1];
    spz[pos] = points[3 * i + 2];
    snx[pos] = normals[3 * i + 0];
    sny[pos] = normals[3 * i + 1];
    snz[pos] = normals[3 * i + 2];
    oidx[pos] = i;
}

// ---------------- pass 4: main gather over sorted stream ----------------
__global__ __launch_bounds__(256) void main_kernel(
    const float* __restrict__ coeff,
    const float* __restrict__ aabb,
    const float* __restrict__ spx, const float* __restrict__ spy, const float* __restrict__ spz,
    const float* __restrict__ snx, const float* __restrict__ sny, const float* __restrict__ snz,
    const int* __restrict__ oidx,
    float* __restrict__ out,
    int n)
{
    const int k = blockIdx.x * blockDim.x + threadIdx.x;
    if (k >= n) return;

    const float px = spx[k], py = spy[k], pz = spz[k];
    const float nx = snx[k], ny = sny[k], nz = snz[k];
    const int oi = oidx[k];

    int ix, iy, iz; float fx, fy, fz;
    grid_coords(aabb, px, py, pz, ix, iy, iz, fx, fy, fz);

    // SH basis, degree 4 -> 16 components
    const float xx = nx * nx, yy = ny * ny, zz = nz * nz;
    const float xy = nx * ny, yz = ny * nz, xz = nx * nz;
    float sh[D2];
    sh[0]  = 0.28209479177387814f;
    sh[1]  = -0.4886025119029199f * ny;
    sh[2]  = 0.4886025119029199f * nz;
    sh[3]  = -0.4886025119029199f * nx;
    sh[4]  = 1.0925484305920792f * xy;
    sh[5]  = -1.0925484305920792f * yz;
    sh[6]  = 0.31539156525252005f * (2.0f * zz - xx - yy);
    sh[7]  = -1.0925484305920792f * xz;
    sh[8]  = 0.5462742152960396f * (xx - yy);
    sh[9]  = -0.5900435899266435f * ny * (3.0f * xx - yy);
    sh[10] = 2.890611442640554f * xy * nz;
    sh[11] = -0.4570457994644658f * ny * (4.0f * zz - xx - yy);
    sh[12] = 0.3731763325901154f * nz * (2.0f * zz - 3.0f * xx - 3.0f * yy);
    sh[13] = -0.4570457994644658f * nx * (4.0f * zz - xx - yy);
    sh[14] = 1.445305721320277f * nz * (xx - yy);
    sh[15] = -0.5900435899266435f * nx * (xx - 3.0f * yy);

    const float wz0 = 1.0f - fz, wz1 = fz;
    float acc0 = 0.0f, acc1 = 0.0f, acc2 = 0.0f;

#pragma unroll
    for (int dx = 0; dx < 2; ++dx) {
        const float wx = dx ? fx : 1.0f - fx;
#pragma unroll
        for (int dy = 0; dy < 2; ++dy) {
            const float wxy = wx * (dy ? fy : 1.0f - fy);
            const int cell = (((ix + dx) * RES + (iy + dy)) * RES + iz) * CSTRIDE;
            const float4* __restrict__ cp = (const float4*)(coeff + cell);
            union { float4 q[24]; float v[96]; } u;
#pragma unroll
            for (int kk = 0; kk < 24; ++kk) u.q[kk] = cp[kk];

            float s00 = 0.f, s01 = 0.f, s02 = 0.f;
            float s10 = 0.f, s11 = 0.f, s12 = 0.f;
#pragma unroll
            for (int j = 0; j < D2; ++j) {
                const float s = sh[j];
                s00 = fmaf(s, u.v[3 * j + 0], s00);
                s01 = fmaf(s, u.v[3 * j + 1], s01);
                s02 = fmaf(s, u.v[3 * j + 2], s02);
                s10 = fmaf(s, u.v[48 + 3 * j + 0], s10);
                s11 = fmaf(s, u.v[48 + 3 * j + 1], s11);
                s12 = fmaf(s, u.v[48 + 3 * j + 2], s12);
            }
            const float w0 = wxy * wz0, w1 = wxy * wz1;
            acc0 = fmaf(w0, s00, fmaf(w1, s10, acc0));
            acc1 = fmaf(w0, s01, fmaf(w1, s11, acc1));
            acc2 = fmaf(w0, s02, fmaf(w1, s12, acc2));
        }
    }

    out[3 * oi + 0] = fmaxf(acc0, 0.0f);
    out[3 * oi + 1] = fmaxf(acc1, 0.0f);
    out[3 * oi + 2] = fmaxf(acc2, 0.0f);
}

// ---------------- fallback (round-1): direct, unsorted ----------------
__global__ __launch_bounds__(256) void direct_kernel(
    const float* __restrict__ coeff,
    const float* __restrict__ aabb,
    const float* __restrict__ points,
    const float* __restrict__ normals,
    float* __restrict__ out,
    int n)
{
    const int i = blockIdx.x * blockDim.x + threadIdx.x;
    if (i >= n) return;
    const float px = points[3 * i + 0], py = points[3 * i + 1], pz = points[3 * i + 2];
    const float nx = normals[3 * i + 0], ny = normals[3 * i + 1], nz = normals[3 * i + 2];
    int ix, iy, iz; float fx, fy, fz;
    grid_coords(aabb, px, py, pz, ix, iy, iz, fx, fy, fz);
    const float xx = nx * nx, yy = ny * ny, zz = nz * nz;
    const float xy = nx * ny, yz = ny * nz, xz = nx * nz;
    float sh[D2];
    sh[0]  = 0.28209479177387814f;
    sh[1]  = -0.4886025119029199f * ny;
    sh[2]  = 0.4886025119029199f * nz;
    sh[3]  = -0.4886025119029199f * nx;
    sh[4]  = 1.0925484305920792f * xy;
    sh[5]  = -1.0925484305920792f * yz;
    sh[6]  = 0.31539156525252005f * (2.0f * zz - xx - yy);
    sh[7]  = -1.0925484305920792f * xz;
    sh[8]  = 0.5462742152960396f * (xx - yy);
    sh[9]  = -0.5900435899266435f * ny * (3.0f * xx - yy);
    sh[10] = 2.890611442640554f * xy * nz;
    sh[11] = -0.4570457994644658f * ny * (4.0f * zz - xx - yy);
    sh[12] = 0.3731763325901154f * nz * (2.0f * zz - 3.0f * xx - 3.0f * yy);
    sh[13] = -0.4570457994644658f * nx * (4.0f * zz - xx - yy);
    sh[14] = 1.445305721320277f * nz * (xx - yy);
    sh[15] = -0.5900435899266435f * nx * (xx - 3.0f * yy);
    const float wz0 = 1.0f - fz, wz1 = fz;
    float acc0 = 0.0f, acc1 = 0.0f, acc2 = 0.0f;
#pragma unroll
    for (int dx = 0; dx < 2; ++dx) {
        const float wx = dx ? fx : 1.0f - fx;
#pragma unroll
        for (int dy = 0; dy < 2; ++dy) {
            const float wxy = wx * (dy ? fy : 1.0f - fy);
            const int cell = (((ix + dx) * RES + (iy + dy)) * RES + iz) * CSTRIDE;
            const float4* __restrict__ cp = (const float4*)(coeff + cell);
            union { float4 q[24]; float v[96]; } u;
#pragma unroll
            for (int kk = 0; kk < 24; ++kk) u.q[kk] = cp[kk];
            float s00 = 0.f, s01 = 0.f, s02 = 0.f;
            float s10 = 0.f, s11 = 0.f, s12 = 0.f;
#pragma unroll
            for (int j = 0; j < D2; ++j) {
                const float s = sh[j];
                s00 = fmaf(s, u.v[3 * j + 0], s00);
                s01 = fmaf(s, u.v[3 * j + 1], s01);
                s02 = fmaf(s, u.v[3 * j + 2], s02);
                s10 = fmaf(s, u.v[48 + 3 * j + 0], s10);
                s11 = fmaf(s, u.v[48 + 3 * j + 1], s11);
                s12 = fmaf(s, u.v[48 + 3 * j + 2], s12);
            }
            const float w0 = wxy * wz0, w1 = wxy * wz1;
            acc0 = fmaf(w0, s00, fmaf(w1, s10, acc0));
            acc1 = fmaf(w0, s01, fmaf(w1, s11, acc1));
            acc2 = fmaf(w0, s02, fmaf(w1, s12, acc2));
        }
    }
    out[3 * i + 0] = fmaxf(acc0, 0.0f);
    out[3 * i + 1] = fmaxf(acc1, 0.0f);
    out[3 * i + 2] = fmaxf(acc2, 0.0f);
}

extern "C" void kernel_launch(void* const* d_in, const int* in_sizes, int n_in,
                              void* d_out, int out_size, void* d_ws, size_t ws_size,
                              hipStream_t stream) {
    const float* coeff   = (const float*)d_in[0];
    const float* aabb    = (const float*)d_in[1];
    const float* points  = (const float*)d_in[2];
    const float* normals = (const float*)d_in[3];
    float* out = (float*)d_out;

    const int n = in_sizes[2] / 3;  // N_PTS
    const int nblk = (n + 255) / 256;

    // workspace layout
    size_t off = 0;
    auto take = [&](size_t bytes) { size_t o = off; off = (off + bytes + 255) & ~(size_t)255; return o; };
    char* ws = (char*)d_ws;
    const size_t o_bin    = take((size_t)n * 4);
    const size_t o_hist   = take((size_t)NBINS * 4);
    const size_t o_cursor = take((size_t)NBINS * 4);
    const size_t o_spx    = take((size_t)n * 4);
    const size_t o_spy    = take((size_t)n * 4);
    const size_t o_spz    = take((size_t)n * 4);
    const size_t o_snx    = take((size_t)n * 4);
    const size_t o_sny    = take((size_t)n * 4);
    const size_t o_snz    = take((size_t)n * 4);
    const size_t o_oidx   = take((size_t)n * 4);
    const size_t needed = off;

    if (ws_size < needed) {
        // not enough scratch: direct (round-1) path
        hipLaunchKernelGGL(direct_kernel, dim3(nblk), dim3(256), 0, stream,
                           coeff, aabb, points, normals, out, n);
        return;
    }

    int* bin_of_point = (int*)(ws + o_bin);
    int* hist   = (int*)(ws + o_hist);
    int* cursor = (int*)(ws + o_cursor);
    float* spx = (float*)(ws + o_spx);
    float* spy = (float*)(ws + o_spy);
    float* spz = (float*)(ws + o_spz);
    float* snx = (float*)(ws + o_snx);
    float* sny = (float*)(ws + o_sny);
    float* snz = (float*)(ws + o_snz);
    int* oidx  = (int*)(ws + o_oidx);

    hipMemsetAsync(hist, 0, (size_t)NBINS * 4, stream);

    hipLaunchKernelGGL(hist_kernel, dim3(nblk), dim3(256), 0, stream,
                       aabb, points, bin_of_point, hist, n);
    hipLaunchKernelGGL(scan_kernel, dim3(1), dim3(256), 0, stream,
                       hist, cursor);
    hipLaunchKernelGGL(scatter_kernel, dim3(nblk), dim3(256), 0, stream,
                       points, normals, bin_of_point, cursor,
                       spx, spy, spz, snx, sny, snz, oidx, n);
    hipLaunchKernelGGL(main_kernel, dim3(nblk), dim3(256), 0, stream,
                       coeff, aabb, spx, spy, spz, snx, sny, snz, oidx, out, n);
}

// Round 3
// 1001.925 us; speedup vs baseline: 1.7065x; 1.6037x over previous
//
#include <hip/hip_runtime.h>

// IrradianceVolumes: out[i,c] = relu( sum_j sh_j(normal_i) * trilerp(coeff[...,j,c], point_i) )
// coeff: [128,128,128,16,3] f32 (403 MB), points/normals: [2M,3] f32, out: [2M,3] f32.
//
// Round 3: one block per 8^3-cell spatial bin. Stream the bin's 9^3-cell halo
// (139,968 B) into LDS once (coalesced), then compute all ~512 points of the bin
// from LDS. Sort is index-only (4-B scatter) to kill round-2's 1.8 GB scatter.

constexpr int RES = 128;
constexpr int D2 = 16;
constexpr int CSTRIDE = D2 * 3;       // 48 floats per cell
constexpr int BIN_SHIFT = 3;          // 8 cells per bin axis
constexpr int BPA = 16;               // bins per axis
constexpr int NBINS = BPA * BPA * BPA;
constexpr int HALO = 9;               // cells per axis incl. +1 halo
constexpr int CELL_F4 = CSTRIDE / 4;  // 12 float4 per cell
constexpr int TOT_F4 = HALO * HALO * HALO * CELL_F4; // 8748 float4 = 139,968 B
constexpr int MAIN_THREADS = 512;
constexpr int LOAD_ITERS = (TOT_F4 + MAIN_THREADS - 1) / MAIN_THREADS + 1; // 18 (clamped)

__device__ __forceinline__ void grid_coords(const float* aabb, float px, float py, float pz,
                                            int& ix, int& iy, int& iz,
                                            float& fx, float& fy, float& fz)
{
    const float a0 = aabb[0], a1 = aabb[1], a2 = aabb[2];
    const float b0 = aabb[3], b1 = aabb[4], b2 = aabb[5];
    float gx = (px - a0) / (b0 - a0) * (float)(RES - 1);
    float gy = (py - a1) / (b1 - a1) * (float)(RES - 1);
    float gz = (pz - a2) / (b2 - a2) * (float)(RES - 1);
    gx = fminf(fmaxf(gx, 0.0f), (float)(RES - 1));
    gy = fminf(fmaxf(gy, 0.0f), (float)(RES - 1));
    gz = fminf(fmaxf(gz, 0.0f), (float)(RES - 1));
    ix = min((int)floorf(gx), RES - 2);
    iy = min((int)floorf(gy), RES - 2);
    iz = min((int)floorf(gz), RES - 2);
    fx = gx - (float)ix;
    fy = gy - (float)iy;
    fz = gz - (float)iz;
}

__device__ __forceinline__ void sh_basis(float nx, float ny, float nz, float* sh)
{
    const float xx = nx * nx, yy = ny * ny, zz = nz * nz;
    const float xy = nx * ny, yz = ny * nz, xz = nx * nz;
    sh[0]  = 0.28209479177387814f;
    sh[1]  = -0.4886025119029199f * ny;
    sh[2]  = 0.4886025119029199f * nz;
    sh[3]  = -0.4886025119029199f * nx;
    sh[4]  = 1.0925484305920792f * xy;
    sh[5]  = -1.0925484305920792f * yz;
    sh[6]  = 0.31539156525252005f * (2.0f * zz - xx - yy);
    sh[7]  = -1.0925484305920792f * xz;
    sh[8]  = 0.5462742152960396f * (xx - yy);
    sh[9]  = -0.5900435899266435f * ny * (3.0f * xx - yy);
    sh[10] = 2.890611442640554f * xy * nz;
    sh[11] = -0.4570457994644658f * ny * (4.0f * zz - xx - yy);
    sh[12] = 0.3731763325901154f * nz * (2.0f * zz - 3.0f * xx - 3.0f * yy);
    sh[13] = -0.4570457994644658f * nx * (4.0f * zz - xx - yy);
    sh[14] = 1.445305721320277f * nz * (xx - yy);
    sh[15] = -0.5900435899266435f * nx * (xx - 3.0f * yy);
}

// ---------------- pass 1: histogram + bin id per point ----------------
__global__ __launch_bounds__(256) void hist_kernel(
    const float* __restrict__ aabb,
    const float* __restrict__ points,
    int* __restrict__ bin_of_point,
    int* __restrict__ hist,
    int n)
{
    const int i = blockIdx.x * blockDim.x + threadIdx.x;
    if (i >= n) return;
    int ix, iy, iz; float fx, fy, fz;
    grid_coords(aabb, points[3 * i + 0], points[3 * i + 1], points[3 * i + 2],
                ix, iy, iz, fx, fy, fz);
    const int bin = (((ix >> BIN_SHIFT) * BPA) + (iy >> BIN_SHIFT)) * BPA + (iz >> BIN_SHIFT);
    bin_of_point[i] = bin;
    atomicAdd(&hist[bin], 1);
}

// ---------------- pass 2: exclusive prefix sum over 4096 bins ----------------
__global__ __launch_bounds__(256) void scan_kernel(
    const int* __restrict__ hist,
    int* __restrict__ binstart,
    int* __restrict__ cursor)
{
    __shared__ int lsum[256];
    const int t = threadIdx.x;
    const int base = t * (NBINS / 256);
    int loc[NBINS / 256];
    int s = 0;
#pragma unroll
    for (int k = 0; k < NBINS / 256; ++k) { loc[k] = hist[base + k]; s += loc[k]; }
    lsum[t] = s;
    __syncthreads();
    for (int off = 1; off < 256; off <<= 1) {
        int v = (t >= off) ? lsum[t - off] : 0;
        __syncthreads();
        lsum[t] += v;
        __syncthreads();
    }
    int run = lsum[t] - s;
#pragma unroll
    for (int k = 0; k < NBINS / 256; ++k) {
        binstart[base + k] = run;
        cursor[base + k] = run;
        run += loc[k];
    }
}

// ---------------- pass 3: scatter original indices into sorted order ----------------
__global__ __launch_bounds__(256) void scatter_kernel(
    const int* __restrict__ bin_of_point,
    int* __restrict__ cursor,
    int* __restrict__ sidx,
    int n)
{
    const int i = blockIdx.x * blockDim.x + threadIdx.x;
    if (i >= n) return;
    const int bin = bin_of_point[i];
    const int pos = atomicAdd(&cursor[bin], 1);
    sidx[pos] = i;
}

// ---------------- pass 4: one block per bin, LDS-staged gather ----------------
__global__ __launch_bounds__(MAIN_THREADS) void main_kernel(
    const float* __restrict__ coeff,
    const float* __restrict__ aabb,
    const float* __restrict__ points,
    const float* __restrict__ normals,
    const int* __restrict__ binstart,
    const int* __restrict__ hist,
    const int* __restrict__ sidx,
    float* __restrict__ out)
{
    extern __shared__ char smem[];
    float4* lds4 = (float4*)smem;

    const int bin = blockIdx.x;
    const int start = binstart[bin];
    const int count = hist[bin];
    if (count == 0) return;

    const int bx = bin >> 8;
    const int by = (bin >> 4) & 15;
    const int bz = bin & 15;
    const int x0 = bx << BIN_SHIFT;
    const int y0 = by << BIN_SHIFT;
    const int z0 = bz << BIN_SHIFT;

    const int tid = threadIdx.x;
    const float4* __restrict__ coeff4 = (const float4*)coeff;

    // ---- stage 9^3-cell halo region into LDS (register-staged for MLP) ----
    float4 r[LOAD_ITERS];
#pragma unroll
    for (int k = 0; k < LOAD_ITERS; ++k) {
        int u = min(tid + k * MAIN_THREADS, TOT_F4 - 1);
        int run = u / (HALO * CELL_F4);            // 0..80  (x*9+y)
        int off = u - run * (HALO * CELL_F4);      // 0..107 within z-run
        int cx = run / HALO, cy = run - cx * HALO;
        int cz = off / CELL_F4, rem = off - cz * CELL_F4;
        int xg = min(x0 + cx, RES - 1);
        int yg = min(y0 + cy, RES - 1);
        int zg = min(z0 + cz, RES - 1);
        r[k] = coeff4[((xg * RES + yg) * RES + zg) * CELL_F4 + rem];
    }
#pragma unroll
    for (int k = 0; k < LOAD_ITERS; ++k) {
        int u = min(tid + k * MAIN_THREADS, TOT_F4 - 1);
        lds4[u] = r[k];
    }
    __syncthreads();

    // ---- compute this bin's points from LDS ----
    for (int p = start + tid; p < start + count; p += MAIN_THREADS) {
        const int i = sidx[p];
        const float px = points[3 * i + 0];
        const float py = points[3 * i + 1];
        const float pz = points[3 * i + 2];
        const float nx = normals[3 * i + 0];
        const float ny = normals[3 * i + 1];
        const float nz = normals[3 * i + 2];

        int ix, iy, iz; float fx, fy, fz;
        grid_coords(aabb, px, py, pz, ix, iy, iz, fx, fy, fz);
        const int lx = ix - x0, ly = iy - y0, lz = iz - z0;

        float sh[D2];
        sh_basis(nx, ny, nz, sh);

        const float wz0 = 1.0f - fz, wz1 = fz;
        float acc0 = 0.0f, acc1 = 0.0f, acc2 = 0.0f;

#pragma unroll
        for (int dx = 0; dx < 2; ++dx) {
            const float wx = dx ? fx : 1.0f - fx;
#pragma unroll
            for (int dy = 0; dy < 2; ++dy) {
                const float wxy = wx * (dy ? fy : 1.0f - fy);
                const int lcell = (((lx + dx) * HALO + (ly + dy)) * HALO + lz) * CELL_F4;
                union { float4 q[24]; float v[96]; } u;
#pragma unroll
                for (int kk = 0; kk < 24; ++kk) u.q[kk] = lds4[lcell + kk];

                float s00 = 0.f, s01 = 0.f, s02 = 0.f;
                float s10 = 0.f, s11 = 0.f, s12 = 0.f;
#pragma unroll
                for (int j = 0; j < D2; ++j) {
                    const float s = sh[j];
                    s00 = fmaf(s, u.v[3 * j + 0], s00);
                    s01 = fmaf(s, u.v[3 * j + 1], s01);
                    s02 = fmaf(s, u.v[3 * j + 2], s02);
                    s10 = fmaf(s, u.v[48 + 3 * j + 0], s10);
                    s11 = fmaf(s, u.v[48 + 3 * j + 1], s11);
                    s12 = fmaf(s, u.v[48 + 3 * j + 2], s12);
                }
                const float w0 = wxy * wz0, w1 = wxy * wz1;
                acc0 = fmaf(w0, s00, fmaf(w1, s10, acc0));
                acc1 = fmaf(w0, s01, fmaf(w1, s11, acc1));
                acc2 = fmaf(w0, s02, fmaf(w1, s12, acc2));
            }
        }

        out[3 * i + 0] = fmaxf(acc0, 0.0f);
        out[3 * i + 1] = fmaxf(acc1, 0.0f);
        out[3 * i + 2] = fmaxf(acc2, 0.0f);
    }
}

// ---------------- fallback: direct, unsorted (round-1) ----------------
__global__ __launch_bounds__(256) void direct_kernel(
    const float* __restrict__ coeff,
    const float* __restrict__ aabb,
    const float* __restrict__ points,
    const float* __restrict__ normals,
    float* __restrict__ out,
    int n)
{
    const int i = blockIdx.x * blockDim.x + threadIdx.x;
    if (i >= n) return;
    const float px = points[3 * i + 0], py = points[3 * i + 1], pz = points[3 * i + 2];
    const float nx = normals[3 * i + 0], ny = normals[3 * i + 1], nz = normals[3 * i + 2];
    int ix, iy, iz; float fx, fy, fz;
    grid_coords(aabb, px, py, pz, ix, iy, iz, fx, fy, fz);
    float sh[D2];
    sh_basis(nx, ny, nz, sh);
    const float wz0 = 1.0f - fz, wz1 = fz;
    float acc0 = 0.0f, acc1 = 0.0f, acc2 = 0.0f;
#pragma unroll
    for (int dx = 0; dx < 2; ++dx) {
        const float wx = dx ? fx : 1.0f - fx;
#pragma unroll
        for (int dy = 0; dy < 2; ++dy) {
            const float wxy = wx * (dy ? fy : 1.0f - fy);
            const int cell = (((ix + dx) * RES + (iy + dy)) * RES + iz) * CSTRIDE;
            const float4* __restrict__ cp = (const float4*)(coeff + cell);
            union { float4 q[24]; float v[96]; } u;
#pragma unroll
            for (int kk = 0; kk < 24; ++kk) u.q[kk] = cp[kk];
            float s00 = 0.f, s01 = 0.f, s02 = 0.f;
            float s10 = 0.f, s11 = 0.f, s12 = 0.f;
#pragma unroll
            for (int j = 0; j < D2; ++j) {
                const float s = sh[j];
                s00 = fmaf(s, u.v[3 * j + 0], s00);
                s01 = fmaf(s, u.v[3 * j + 1], s01);
                s02 = fmaf(s, u.v[3 * j + 2], s02);
                s10 = fmaf(s, u.v[48 + 3 * j + 0], s10);
                s11 = fmaf(s, u.v[48 + 3 * j + 1], s11);
                s12 = fmaf(s, u.v[48 + 3 * j + 2], s12);
            }
            const float w0 = wxy * wz0, w1 = wxy * wz1;
            acc0 = fmaf(w0, s00, fmaf(w1, s10, acc0));
            acc1 = fmaf(w0, s01, fmaf(w1, s11, acc1));
            acc2 = fmaf(w0, s02, fmaf(w1, s12, acc2));
        }
    }
    out[3 * i + 0] = fmaxf(acc0, 0.0f);
    out[3 * i + 1] = fmaxf(acc1, 0.0f);
    out[3 * i + 2] = fmaxf(acc2, 0.0f);
}

extern "C" void kernel_launch(void* const* d_in, const int* in_sizes, int n_in,
                              void* d_out, int out_size, void* d_ws, size_t ws_size,
                              hipStream_t stream) {
    const float* coeff   = (const float*)d_in[0];
    const float* aabb    = (const float*)d_in[1];
    const float* points  = (const float*)d_in[2];
    const float* normals = (const float*)d_in[3];
    float* out = (float*)d_out;

    const int n = in_sizes[2] / 3;  // N_PTS
    const int nblk = (n + 255) / 256;

    size_t off = 0;
    auto take = [&](size_t bytes) { size_t o = off; off = (off + bytes + 255) & ~(size_t)255; return o; };
    char* ws = (char*)d_ws;
    const size_t o_bin      = take((size_t)n * 4);
    const size_t o_hist     = take((size_t)NBINS * 4);
    const size_t o_binstart = take((size_t)NBINS * 4);
    const size_t o_cursor   = take((size_t)NBINS * 4);
    const size_t o_sidx     = take((size_t)n * 4);
    const size_t needed = off;

    if (ws_size < needed) {
        hipLaunchKernelGGL(direct_kernel, dim3(nblk), dim3(256), 0, stream,
                           coeff, aabb, points, normals, out, n);
        return;
    }

    int* bin_of_point = (int*)(ws + o_bin);
    int* hist     = (int*)(ws + o_hist);
    int* binstart = (int*)(ws + o_binstart);
    int* cursor   = (int*)(ws + o_cursor);
    int* sidx     = (int*)(ws + o_sidx);

    hipMemsetAsync(hist, 0, (size_t)NBINS * 4, stream);

    hipLaunchKernelGGL(hist_kernel, dim3(nblk), dim3(256), 0, stream,
                       aabb, points, bin_of_point, hist, n);
    hipLaunchKernelGGL(scan_kernel, dim3(1), dim3(256), 0, stream,
                       hist, binstart, cursor);
    hipLaunchKernelGGL(scatter_kernel, dim3(nblk), dim3(256), 0, stream,
                       bin_of_point, cursor, sidx, n);
    hipLaunchKernelGGL(main_kernel, dim3(NBINS), dim3(MAIN_THREADS),
                       TOT_F4 * sizeof(float4), stream,
                       coeff, aabb, points, normals, binstart, hist, sidx, out);
}

// Round 4
// 926.264 us; speedup vs baseline: 1.8459x; 1.0817x over previous
//
#include <hip/hip_runtime.h>

// IrradianceVolumes: out[i,c] = relu( sum_j sh_j(normal_i) * trilerp(coeff[...,j,c], point_i) )
// coeff: [128,128,128,16,3] f32 (403 MB), points/normals: [2M,3] f32, out: [2M,3] f32.
//
// Round 4:
//  - atomic counters padded to 1/cacheline (round-3 sort cost ~700us from
//    same-line L2 RMW serialization: 16 counters/64B line).
//  - bins 4x8x8 cells, halo 5x9x9 = 77,760 B LDS -> 2 blocks/CU so one block's
//    global->LDS staging overlaps the other's LDS compute.

constexpr int RES = 128;
constexpr int D2 = 16;
constexpr int CSTRIDE = D2 * 3;       // 48 floats per cell
constexpr int CELL_F4 = CSTRIDE / 4;  // 12 float4 per cell

// bins: x split by 4 (shift 2), y/z by 8 (shift 3)
constexpr int NBX = 32, NBY = 16, NBZ = 16;
constexpr int NBINS = NBX * NBY * NBZ;     // 8192
constexpr int HX = 5, HY = 9, HZ = 9;      // halo cells per axis
constexpr int TOT_F4 = HX * HY * HZ * CELL_F4; // 4860 float4 = 77,760 B
constexpr int MAIN_THREADS = 256;
constexpr int LOAD_ITERS = (TOT_F4 + MAIN_THREADS - 1) / MAIN_THREADS; // 19
constexpr int PAD = 16; // ints per counter line (64 B)

__device__ __forceinline__ void grid_coords(const float* aabb, float px, float py, float pz,
                                            int& ix, int& iy, int& iz,
                                            float& fx, float& fy, float& fz)
{
    const float a0 = aabb[0], a1 = aabb[1], a2 = aabb[2];
    const float b0 = aabb[3], b1 = aabb[4], b2 = aabb[5];
    float gx = (px - a0) / (b0 - a0) * (float)(RES - 1);
    float gy = (py - a1) / (b1 - a1) * (float)(RES - 1);
    float gz = (pz - a2) / (b2 - a2) * (float)(RES - 1);
    gx = fminf(fmaxf(gx, 0.0f), (float)(RES - 1));
    gy = fminf(fmaxf(gy, 0.0f), (float)(RES - 1));
    gz = fminf(fmaxf(gz, 0.0f), (float)(RES - 1));
    ix = min((int)floorf(gx), RES - 2);
    iy = min((int)floorf(gy), RES - 2);
    iz = min((int)floorf(gz), RES - 2);
    fx = gx - (float)ix;
    fy = gy - (float)iy;
    fz = gz - (float)iz;
}

__device__ __forceinline__ int bin_of(int ix, int iy, int iz)
{
    return (((ix >> 2) * NBY) + (iy >> 3)) * NBZ + (iz >> 3);
}

__device__ __forceinline__ void sh_basis(float nx, float ny, float nz, float* sh)
{
    const float xx = nx * nx, yy = ny * ny, zz = nz * nz;
    const float xy = nx * ny, yz = ny * nz, xz = nx * nz;
    sh[0]  = 0.28209479177387814f;
    sh[1]  = -0.4886025119029199f * ny;
    sh[2]  = 0.4886025119029199f * nz;
    sh[3]  = -0.4886025119029199f * nx;
    sh[4]  = 1.0925484305920792f * xy;
    sh[5]  = -1.0925484305920792f * yz;
    sh[6]  = 0.31539156525252005f * (2.0f * zz - xx - yy);
    sh[7]  = -1.0925484305920792f * xz;
    sh[8]  = 0.5462742152960396f * (xx - yy);
    sh[9]  = -0.5900435899266435f * ny * (3.0f * xx - yy);
    sh[10] = 2.890611442640554f * xy * nz;
    sh[11] = -0.4570457994644658f * ny * (4.0f * zz - xx - yy);
    sh[12] = 0.3731763325901154f * nz * (2.0f * zz - 3.0f * xx - 3.0f * yy);
    sh[13] = -0.4570457994644658f * nx * (4.0f * zz - xx - yy);
    sh[14] = 1.445305721320277f * nz * (xx - yy);
    sh[15] = -0.5900435899266435f * nx * (xx - 3.0f * yy);
}

// ---------------- pass 1: histogram (padded counters) + bin id per point ----------------
__global__ __launch_bounds__(256) void hist_kernel(
    const float* __restrict__ aabb,
    const float* __restrict__ points,
    int* __restrict__ bin_of_point,
    int* __restrict__ hist_p,     // NBINS * PAD
    int n)
{
    const int i = blockIdx.x * blockDim.x + threadIdx.x;
    if (i >= n) return;
    int ix, iy, iz; float fx, fy, fz;
    grid_coords(aabb, points[3 * i + 0], points[3 * i + 1], points[3 * i + 2],
                ix, iy, iz, fx, fy, fz);
    const int bin = bin_of(ix, iy, iz);
    bin_of_point[i] = bin;
    atomicAdd(&hist_p[bin * PAD], 1);
}

// ---------------- pass 2: exclusive prefix sum over 8192 bins ----------------
__global__ __launch_bounds__(256) void scan_kernel(
    const int* __restrict__ hist_p,
    int* __restrict__ binstart,   // compact NBINS
    int* __restrict__ cursor_p)   // NBINS * PAD
{
    __shared__ int lsum[256];
    const int t = threadIdx.x;
    constexpr int PER = NBINS / 256; // 32
    const int base = t * PER;
    int loc[PER];
    int s = 0;
#pragma unroll
    for (int k = 0; k < PER; ++k) { loc[k] = hist_p[(base + k) * PAD]; s += loc[k]; }
    lsum[t] = s;
    __syncthreads();
    for (int off = 1; off < 256; off <<= 1) {
        int v = (t >= off) ? lsum[t - off] : 0;
        __syncthreads();
        lsum[t] += v;
        __syncthreads();
    }
    int run = lsum[t] - s;
#pragma unroll
    for (int k = 0; k < PER; ++k) {
        binstart[base + k] = run;
        cursor_p[(base + k) * PAD] = run;
        run += loc[k];
    }
}

// ---------------- pass 3: scatter original indices (padded cursors) ----------------
__global__ __launch_bounds__(256) void scatter_kernel(
    const int* __restrict__ bin_of_point,
    int* __restrict__ cursor_p,
    int* __restrict__ sidx,
    int n)
{
    const int i = blockIdx.x * blockDim.x + threadIdx.x;
    if (i >= n) return;
    const int bin = bin_of_point[i];
    const int pos = atomicAdd(&cursor_p[bin * PAD], 1);
    sidx[pos] = i;
}

// ---------------- pass 4: one block per bin, LDS-staged gather ----------------
__global__ __launch_bounds__(MAIN_THREADS) void main_kernel(
    const float* __restrict__ coeff,
    const float* __restrict__ aabb,
    const float* __restrict__ points,
    const float* __restrict__ normals,
    const int* __restrict__ binstart,
    const int* __restrict__ hist_p,
    const int* __restrict__ sidx,
    float* __restrict__ out)
{
    extern __shared__ char smem[];
    float4* lds4 = (float4*)smem;

    const int bin = blockIdx.x;
    const int start = binstart[bin];
    const int count = hist_p[bin * PAD];
    if (count == 0) return;

    const int bx = bin / (NBY * NBZ);
    const int by = (bin / NBZ) % NBY;
    const int bz = bin % NBZ;
    const int x0 = bx << 2;
    const int y0 = by << 3;
    const int z0 = bz << 3;

    const int tid = threadIdx.x;
    const float4* __restrict__ coeff4 = (const float4*)coeff;

    // ---- stage 5x9x9-cell halo region into LDS (lane-contiguous, coalesced) ----
#pragma unroll
    for (int k = 0; k < LOAD_ITERS; ++k) {
        const int u = tid + k * MAIN_THREADS;
        if (u < TOT_F4) {
            int cx = u / (HY * HZ * CELL_F4);            // /972
            int r1 = u - cx * (HY * HZ * CELL_F4);
            int cy = r1 / (HZ * CELL_F4);                // /108
            int r2 = r1 - cy * (HZ * CELL_F4);
            int cz = r2 / CELL_F4;                       // /12
            int kk = r2 - cz * CELL_F4;
            int xg = min(x0 + cx, RES - 1);
            int yg = min(y0 + cy, RES - 1);
            int zg = min(z0 + cz, RES - 1);
            lds4[u] = coeff4[((xg * RES + yg) * RES + zg) * CELL_F4 + kk];
        }
    }
    __syncthreads();

    // ---- compute this bin's points from LDS ----
    for (int p = start + tid; p < start + count; p += MAIN_THREADS) {
        const int i = sidx[p];
        const float px = points[3 * i + 0];
        const float py = points[3 * i + 1];
        const float pz = points[3 * i + 2];
        const float nx = normals[3 * i + 0];
        const float ny = normals[3 * i + 1];
        const float nz = normals[3 * i + 2];

        int ix, iy, iz; float fx, fy, fz;
        grid_coords(aabb, px, py, pz, ix, iy, iz, fx, fy, fz);
        const int lx = ix - x0, ly = iy - y0, lz = iz - z0;

        float sh[D2];
        sh_basis(nx, ny, nz, sh);

        const float wz0 = 1.0f - fz, wz1 = fz;
        float acc0 = 0.0f, acc1 = 0.0f, acc2 = 0.0f;

#pragma unroll
        for (int dx = 0; dx < 2; ++dx) {
            const float wx = dx ? fx : 1.0f - fx;
#pragma unroll
            for (int dy = 0; dy < 2; ++dy) {
                const float wxy = wx * (dy ? fy : 1.0f - fy);
                const int lcell = (((lx + dx) * HY + (ly + dy)) * HZ + lz) * CELL_F4;
                union { float4 q[24]; float v[96]; } u;
#pragma unroll
                for (int kk = 0; kk < 24; ++kk) u.q[kk] = lds4[lcell + kk];

                float s00 = 0.f, s01 = 0.f, s02 = 0.f;
                float s10 = 0.f, s11 = 0.f, s12 = 0.f;
#pragma unroll
                for (int j = 0; j < D2; ++j) {
                    const float s = sh[j];
                    s00 = fmaf(s, u.v[3 * j + 0], s00);
                    s01 = fmaf(s, u.v[3 * j + 1], s01);
                    s02 = fmaf(s, u.v[3 * j + 2], s02);
                    s10 = fmaf(s, u.v[48 + 3 * j + 0], s10);
                    s11 = fmaf(s, u.v[48 + 3 * j + 1], s11);
                    s12 = fmaf(s, u.v[48 + 3 * j + 2], s12);
                }
                const float w0 = wxy * wz0, w1 = wxy * wz1;
                acc0 = fmaf(w0, s00, fmaf(w1, s10, acc0));
                acc1 = fmaf(w0, s01, fmaf(w1, s11, acc1));
                acc2 = fmaf(w0, s02, fmaf(w1, s12, acc2));
            }
        }

        out[3 * i + 0] = fmaxf(acc0, 0.0f);
        out[3 * i + 1] = fmaxf(acc1, 0.0f);
        out[3 * i + 2] = fmaxf(acc2, 0.0f);
    }
}

// ---------------- fallback: direct, unsorted (round-1) ----------------
__global__ __launch_bounds__(256) void direct_kernel(
    const float* __restrict__ coeff,
    const float* __restrict__ aabb,
    const float* __restrict__ points,
    const float* __restrict__ normals,
    float* __restrict__ out,
    int n)
{
    const int i = blockIdx.x * blockDim.x + threadIdx.x;
    if (i >= n) return;
    const float px = points[3 * i + 0], py = points[3 * i + 1], pz = points[3 * i + 2];
    const float nx = normals[3 * i + 0], ny = normals[3 * i + 1], nz = normals[3 * i + 2];
    int ix, iy, iz; float fx, fy, fz;
    grid_coords(aabb, px, py, pz, ix, iy, iz, fx, fy, fz);
    float sh[D2];
    sh_basis(nx, ny, nz, sh);
    const float wz0 = 1.0f - fz, wz1 = fz;
    float acc0 = 0.0f, acc1 = 0.0f, acc2 = 0.0f;
#pragma unroll
    for (int dx = 0; dx < 2; ++dx) {
        const float wx = dx ? fx : 1.0f - fx;
#pragma unroll
        for (int dy = 0; dy < 2; ++dy) {
            const float wxy = wx * (dy ? fy : 1.0f - fy);
            const int cell = (((ix + dx) * RES + (iy + dy)) * RES + iz) * CSTRIDE;
            const float4* __restrict__ cp = (const float4*)(coeff + cell);
            union { float4 q[24]; float v[96]; } u;
#pragma unroll
            for (int kk = 0; kk < 24; ++kk) u.q[kk] = cp[kk];
            float s00 = 0.f, s01 = 0.f, s02 = 0.f;
            float s10 = 0.f, s11 = 0.f, s12 = 0.f;
#pragma unroll
            for (int j = 0; j < D2; ++j) {
                const float s = sh[j];
                s00 = fmaf(s, u.v[3 * j + 0], s00);
                s01 = fmaf(s, u.v[3 * j + 1], s01);
                s02 = fmaf(s, u.v[3 * j + 2], s02);
                s10 = fmaf(s, u.v[48 + 3 * j + 0], s10);
                s11 = fmaf(s, u.v[48 + 3 * j + 1], s11);
                s12 = fmaf(s, u.v[48 + 3 * j + 2], s12);
            }
            const float w0 = wxy * wz0, w1 = wxy * wz1;
            acc0 = fmaf(w0, s00, fmaf(w1, s10, acc0));
            acc1 = fmaf(w0, s01, fmaf(w1, s11, acc1));
            acc2 = fmaf(w0, s02, fmaf(w1, s12, acc2));
        }
    }
    out[3 * i + 0] = fmaxf(acc0, 0.0f);
    out[3 * i + 1] = fmaxf(acc1, 0.0f);
    out[3 * i + 2] = fmaxf(acc2, 0.0f);
}

extern "C" void kernel_launch(void* const* d_in, const int* in_sizes, int n_in,
                              void* d_out, int out_size, void* d_ws, size_t ws_size,
                              hipStream_t stream) {
    const float* coeff   = (const float*)d_in[0];
    const float* aabb    = (const float*)d_in[1];
    const float* points  = (const float*)d_in[2];
    const float* normals = (const float*)d_in[3];
    float* out = (float*)d_out;

    const int n = in_sizes[2] / 3;  // N_PTS
    const int nblk = (n + 255) / 256;

    size_t off = 0;
    auto take = [&](size_t bytes) { size_t o = off; off = (off + bytes + 255) & ~(size_t)255; return o; };
    char* ws = (char*)d_ws;
    const size_t o_bin      = take((size_t)n * 4);
    const size_t o_hist     = take((size_t)NBINS * PAD * 4);
    const size_t o_binstart = take((size_t)NBINS * 4);
    const size_t o_cursor   = take((size_t)NBINS * PAD * 4);
    const size_t o_sidx     = take((size_t)n * 4);
    const size_t needed = off;

    if (ws_size < needed) {
        hipLaunchKernelGGL(direct_kernel, dim3(nblk), dim3(256), 0, stream,
                           coeff, aabb, points, normals, out, n);
        return;
    }

    int* bin_of_point = (int*)(ws + o_bin);
    int* hist_p   = (int*)(ws + o_hist);
    int* binstart = (int*)(ws + o_binstart);
    int* cursor_p = (int*)(ws + o_cursor);
    int* sidx     = (int*)(ws + o_sidx);

    hipMemsetAsync(hist_p, 0, (size_t)NBINS * PAD * 4, stream);

    hipLaunchKernelGGL(hist_kernel, dim3(nblk), dim3(256), 0, stream,
                       aabb, points, bin_of_point, hist_p, n);
    hipLaunchKernelGGL(scan_kernel, dim3(1), dim3(256), 0, stream,
                       hist_p, binstart, cursor_p);
    hipLaunchKernelGGL(scatter_kernel, dim3(nblk), dim3(256), 0, stream,
                       bin_of_point, cursor_p, sidx, n);
    hipLaunchKernelGGL(main_kernel, dim3(NBINS), dim3(MAIN_THREADS),
                       TOT_F4 * sizeof(float4), stream,
                       coeff, aabb, points, normals, binstart, hist_p, sidx, out);
}